// Round 6
// baseline (266.872 us; speedup 1.0000x reference)
//
#include <hip/hip_runtime.h>

// Fused 2-layer GRU + FC for (B=4096, L=128, IN=16, H=128, NC=24).
// 256 blocks x 512 threads (1 block/CU); block = 16 batch rows, wave w owns
// h-cols [16w,16w+16). Weights pinned in VGPRs/AGPRs via empty inline asm.
// Layer2 runs one step behind layer1 => single barrier per step.
//
// Round 3: epilogue trans diet (exp2-scaled weights, shared rcp, zero-C MFMA).
// Round 4: packed-f32 epilogue + reg prefetch -> REGRESSED (scratch spills).
// Round 5: pk epilogue, clean staging -> 213.5us; latency- not issue-bound.
// Round 6: x-projection hoist -> null (212us) + minor spill. Reverted.
// Round 7: LDS stride change (conflict-free) but ax guard removed -> NaN:
//   at tt=31, q>=2 lanes read uninitialized XS-pad; MFMA NaN*0 = NaN.
// Round 8 (this version): same conflict-free strides, ax guard RESTORED.
//   HS 136->140 halves (280B = 70 dwords == 6 mod 32: 16 rows AND 16 lanes
//   map to distinct banks; old 272B stride had rows q/q+2 and lanes c/c+8
//   colliding 2-way = the constant 9.1M SQ_LDS_BANK_CONFLICT). Rows now
//   8B-aligned only, so h fragments load as 2x ds_read_b64 (each phase
//   conflict-free). Same for xl (XS 520->524).

typedef _Float16 half_t;
typedef _Float16 half8 __attribute__((ext_vector_type(8)));
typedef _Float16 half4v __attribute__((ext_vector_type(4)));
typedef float f32x4 __attribute__((ext_vector_type(4)));

#define BB 16      // batch rows per block
#define HS 140     // h row stride (halves): 280B = 70 dwords == 6 mod 32 -> conflict-free
#define XS 524     // x chunk row stride (halves): 1048B = 262 dwords == 6 mod 32

#define NL2E (-1.442695041f)   // -log2(e)  : r,z gates (sigmoid via 2^-x)
#define L2E2 (2.885390082f)    // 2*log2(e) : n gate    (tanh via 2^{2a*log2e})

static __device__ __forceinline__ f32x4 mfma16(half8 a, half8 b, f32x4 c) {
  return __builtin_amdgcn_mfma_f32_16x16x32_f16(a, b, c, 0, 0, 0);
}

// Pin a fragment into registers: value becomes asm-defined => cannot be
// rematerialized from global memory inside the recurrence loop.
static __device__ __forceinline__ void pin(half8& v) {
  f32x4 t = __builtin_bit_cast(f32x4, v);
  asm volatile("" : "+v"(t));
  v = __builtin_bit_cast(half8, t);
}

static __device__ __forceinline__ half8 zero8() {
  half8 v;
#pragma unroll
  for (int i = 0; i < 8; ++i) v[i] = (half_t)0.f;
  return v;
}

// 8 halves from an 8B-aligned LDS address: two ds_read_b64 (rows are only
// 8B-aligned at the 280B stride; each b64 phase is bank-conflict-free).
static __device__ __forceinline__ half8 ld8h(const half_t* __restrict__ p) {
  half4v lo = *(const half4v*)p;
  half4v hi = *(const half4v*)(p + 4);
  return __builtin_shufflevector(lo, hi, 0, 1, 2, 3, 4, 5, 6, 7);
}

static __device__ __forceinline__ half8 ldw8s(const float* __restrict__ p, float s) {
  float4 a = *(const float4*)p;
  float4 b = *(const float4*)(p + 4);
  half8 r;
  r[0] = (half_t)(a.x * s); r[1] = (half_t)(a.y * s);
  r[2] = (half_t)(a.z * s); r[3] = (half_t)(a.w * s);
  r[4] = (half_t)(b.x * s); r[5] = (half_t)(b.y * s);
  r[6] = (half_t)(b.z * s); r[7] = (half_t)(b.w * s);
  return r;
}

static __device__ __forceinline__ float ex2(float x) { return __builtin_amdgcn_exp2f(x); }
static __device__ __forceinline__ float rcpa(float x) { return __builtin_amdgcn_rcpf(x); }

__global__ __launch_bounds__(512, 2) void gru_fused(
    const float* __restrict__ x,                                    // (4096,2,1024)
    const float* __restrict__ wih1, const float* __restrict__ whh1, // (384,16),(384,128)
    const float* __restrict__ bih1, const float* __restrict__ bhh1,
    const float* __restrict__ wih2, const float* __restrict__ whh2, // (384,128)x2
    const float* __restrict__ bih2, const float* __restrict__ bhh2,
    const float* __restrict__ fcw, const float* __restrict__ fcb,   // (24,128),(24,)
    float* __restrict__ out)                                        // (4096,24)
{
  __shared__ __align__(16) half_t xl[BB][XS];        // 16768 B
  __shared__ __align__(16) half_t h1b[2][BB][HS];    //  8960 B
  __shared__ __align__(16) half_t h2b[2][BB][HS];    //  8960 B
  __shared__ float h2f[BB][129];                     //  8256 B

  const int tid = threadIdx.x;
  const int lane = tid & 63;
  const int wv = tid >> 6;      // wave 0..7
  const int q = lane >> 4;      // quad 0..3
  const int c = lane & 15;
  const int jc = wv * 16 + c;   // this lane's h-column (0..127)
  const int s0 = blockIdx.x * BB;

  // zero both parity buffers of both states (layer2 MFMAs run unguarded at i=0)
  for (int i = tid; i < 2 * BB * HS; i += 512) {
    ((half_t*)h1b)[i] = (half_t)0.f;
    ((half_t*)h2b)[i] = (half_t)0.f;
  }

  // biases in log2-units. r/z biases fold multiplicatively: e^{-x-b} = 2^{acc}*eb.
  const float eb1r = ex2(NL2E * (bih1[jc] + bhh1[jc]));
  const float eb1z = ex2(NL2E * (bih1[128 + jc] + bhh1[128 + jc]));
  const float b1in = L2E2 * bih1[256 + jc];
  const float b1hn = L2E2 * bhh1[256 + jc];
  const float eb2r = ex2(NL2E * (bih2[jc] + bhh2[jc]));
  const float eb2z = ex2(NL2E * (bih2[128 + jc] + bhh2[128 + jc]));
  const float b2in = L2E2 * bih2[256 + jc];
  const float b2hn = L2E2 * bhh2[256 + jc];

  // weight B-fragments: lane holds W[n=jc(+g*128)][k = kk*32 + q*8 + j],
  // pre-scaled: r,z by -log2e; n by 2*log2e.
  half8 wi1r, wi1z, wi1n;
  if (q < 2) {  // real K=16, quads 2..3 are zero-pad
    wi1r = ldw8s(wih1 + (0 * 128 + jc) * 16 + q * 8, NL2E);
    wi1z = ldw8s(wih1 + (1 * 128 + jc) * 16 + q * 8, NL2E);
    wi1n = ldw8s(wih1 + (2 * 128 + jc) * 16 + q * 8, L2E2);
  } else {
    wi1r = zero8(); wi1z = zero8(); wi1n = zero8();
  }
  pin(wi1r); pin(wi1z); pin(wi1n);

  half8 wh1r[4], wh1z[4], wh1n[4], wi2r[4], wi2z[4], wi2n[4], wh2r[4], wh2z[4], wh2n[4];
#pragma unroll
  for (int kk = 0; kk < 4; ++kk) {
    const int ko = kk * 32 + q * 8;
    wh1r[kk] = ldw8s(whh1 + (0 * 128 + jc) * 128 + ko, NL2E);
    wh1z[kk] = ldw8s(whh1 + (1 * 128 + jc) * 128 + ko, NL2E);
    wh1n[kk] = ldw8s(whh1 + (2 * 128 + jc) * 128 + ko, L2E2);
    wi2r[kk] = ldw8s(wih2 + (0 * 128 + jc) * 128 + ko, NL2E);
    wi2z[kk] = ldw8s(wih2 + (1 * 128 + jc) * 128 + ko, NL2E);
    wi2n[kk] = ldw8s(wih2 + (2 * 128 + jc) * 128 + ko, L2E2);
    wh2r[kk] = ldw8s(whh2 + (0 * 128 + jc) * 128 + ko, NL2E);
    wh2z[kk] = ldw8s(whh2 + (1 * 128 + jc) * 128 + ko, NL2E);
    wh2n[kk] = ldw8s(whh2 + (2 * 128 + jc) * 128 + ko, L2E2);
    pin(wh1r[kk]); pin(wh1z[kk]); pin(wh1n[kk]);
    pin(wi2r[kk]); pin(wi2z[kk]); pin(wi2n[kk]);
    pin(wh2r[kk]); pin(wh2z[kk]); pin(wh2n[kk]);
  }

  // fp32 hidden state, lane-resident: rows m = 4q+r, col jc
  float h1p[4] = {0.f, 0.f, 0.f, 0.f};
  float h2p[4] = {0.f, 0.f, 0.f, 0.f};

#pragma unroll 1
  for (int tc = 0; tc < 4; ++tc) {
    // stage x[s][ch][tc*256 .. +255] -> xl[s][tl*16 + ch*8 + k], fp16
#pragma unroll
    for (int it = 0; it < 4; ++it) {
      int idx = tid + it * 512;         // 0..2047 float4s
      int s = idx >> 7;
      int rem = idx & 127;
      int ch = rem >> 6;
      int i4 = rem & 63;
      const float4 v = *(const float4*)(x + (size_t)(s0 + s) * 2048 + ch * 1024 + tc * 256 + i4 * 4);
      half4v hv;
      hv[0] = (half_t)v.x; hv[1] = (half_t)v.y; hv[2] = (half_t)v.z; hv[3] = (half_t)v.w;
      *(half4v*)&xl[s][(i4 >> 1) * 16 + ch * 8 + (i4 & 1) * 4] = hv;
    }
    __syncthreads();

#pragma unroll 2
    for (int tt = 0; tt < 32; ++tt) {
      const int i = tc * 32 + tt;      // layer1 step index; layer2 does step i-1
      const int rb = i & 1;            // compile-time after unroll-2
      const int wb = rb ^ 1;
      const float l2m = (i > 0) ? 1.f : 0.f;   // uniform; kills i=0 garbage h2
      const f32x4 kZ = {0.f, 0.f, 0.f, 0.f};

      // guard is required: q>=2 addresses can hit uninitialized LDS at tt=31,
      // and MFMA NaN*0 = NaN (round-7 failure). Keep zero8 for pad quads.
      half8 ax = zero8();
      if (q < 2) ax = ld8h(&xl[c][tt * 16 + q * 8]);
      half8 ah0 = ld8h(&h1b[rb][c][q * 8]);   // h1[i-1], kk=0
      half8 a20 = ld8h(&h2b[rb][c][q * 8]);   // h2[i-2], kk=0

      // all 12 chains start from a zero C operand (no bias-splat movs)
      f32x4 ar  = mfma16(ax, wi1r, kZ);
      f32x4 az  = mfma16(ax, wi1z, kZ);
      f32x4 ain = mfma16(ax, wi1n, kZ);
      f32x4 ahn = mfma16(ah0, wh1n[0], kZ);
      ar = mfma16(ah0, wh1r[0], ar);
      az = mfma16(ah0, wh1z[0], az);
      f32x4 cr  = mfma16(ah0, wi2r[0], kZ);
      f32x4 cz  = mfma16(ah0, wi2z[0], kZ);
      f32x4 cin = mfma16(ah0, wi2n[0], kZ);
      f32x4 chn = mfma16(a20, wh2n[0], kZ);
      cr = mfma16(a20, wh2r[0], cr);
      cz = mfma16(a20, wh2z[0], cz);
#pragma unroll
      for (int kk = 1; kk < 4; ++kk) {
        half8 ah = ld8h(&h1b[rb][c][kk * 32 + q * 8]);  // h1[i-1]
        half8 a2 = ld8h(&h2b[rb][c][kk * 32 + q * 8]);  // h2[i-2]
        ar  = mfma16(ah, wh1r[kk], ar);
        az  = mfma16(ah, wh1z[kk], az);
        ahn = mfma16(ah, wh1n[kk], ahn);
        cr  = mfma16(ah, wi2r[kk], cr);   // layer2 input = h1[i-1]
        cz  = mfma16(ah, wi2z[kk], cz);
        cin = mfma16(ah, wi2n[kk], cin);
        cr  = mfma16(a2, wh2r[kk], cr);
        cz  = mfma16(a2, wh2z[kk], cz);
        chn = mfma16(a2, wh2n[kk], chn);
      }

      // ---- epilogue, both layers, scalar (max ILP) ----
      float C1[4], rg1[4], zg1[4], C2[4], rg2[4], zg2[4];
#pragma unroll
      for (int r = 0; r < 4; ++r) {
        float er = ex2(ar[r]);
        float ez = ex2(az[r]);
        float A  = fmaf(er, eb1r, 1.f);
        float Bv = fmaf(ez, eb1z, 1.f);
        float R  = rcpa(A * Bv);
        rg1[r] = R * Bv; zg1[r] = R * A;
        float av = fmaf(rg1[r], ahn[r] + b1hn, ain[r] + b1in);
        C1[r] = 1.f + ex2(av);
      }
#pragma unroll
      for (int r = 0; r < 4; ++r) {
        float er = ex2(cr[r]);
        float ez = ex2(cz[r]);
        float A  = fmaf(er, eb2r, 1.f);
        float Bv = fmaf(ez, eb2z, 1.f);
        float R  = rcpa(A * Bv);
        rg2[r] = R * Bv; zg2[r] = R * A;
        float av = fmaf(rg2[r], chn[r] + b2hn, cin[r] + b2in);
        C2[r] = 1.f + ex2(av);
      }
#pragma unroll
      for (int p = 0; p < 4; p += 2) {
        // layer1 tanh pair + update
        float R1 = rcpa(C1[p] * C1[p + 1]);
        float n0 = fmaf(R1 * C1[p + 1], -2.f, 1.f);
        float n1 = fmaf(R1 * C1[p],     -2.f, 1.f);
        float e0 = fmaf(zg1[p],     h1p[p]     - n0, n0);   // (1-z)n + z h
        float e1 = fmaf(zg1[p + 1], h1p[p + 1] - n1, n1);
        h1p[p] = e0; h1p[p + 1] = e1;
        h1b[wb][q * 4 + p][jc]     = (half_t)e0;
        h1b[wb][q * 4 + p + 1][jc] = (half_t)e1;
        // layer2 tanh pair + masked update (mask=0 only at i==0)
        float R2 = rcpa(C2[p] * C2[p + 1]);
        float m0 = fmaf(R2 * C2[p + 1], -2.f, 1.f);
        float m1 = fmaf(R2 * C2[p],     -2.f, 1.f);
        float g0 = fmaf(zg2[p],     h2p[p]     - m0, m0) * l2m;
        float g1 = fmaf(zg2[p + 1], h2p[p + 1] - m1, m1) * l2m;
        h2p[p] = g0; h2p[p + 1] = g1;
        h2b[wb][q * 4 + p][jc]     = (half_t)g0;
        h2b[wb][q * 4 + p + 1][jc] = (half_t)g1;
      }
      __syncthreads();
    }
  }

  // final layer2 step 127: h1[127] & h2[126] live in parity-0 buffers (i=128)
  {
    const f32x4 kZ = {0.f, 0.f, 0.f, 0.f};
    half8 a10 = ld8h(&h1b[0][c][q * 8]);
    half8 a20 = ld8h(&h2b[0][c][q * 8]);
    f32x4 cr  = mfma16(a10, wi2r[0], kZ);
    f32x4 cz  = mfma16(a10, wi2z[0], kZ);
    f32x4 cin = mfma16(a10, wi2n[0], kZ);
    f32x4 chn = mfma16(a20, wh2n[0], kZ);
    cr = mfma16(a20, wh2r[0], cr);
    cz = mfma16(a20, wh2z[0], cz);
#pragma unroll
    for (int kk = 1; kk < 4; ++kk) {
      half8 a1 = ld8h(&h1b[0][c][kk * 32 + q * 8]);
      half8 a2 = ld8h(&h2b[0][c][kk * 32 + q * 8]);
      cr  = mfma16(a1, wi2r[kk], cr);
      cz  = mfma16(a1, wi2z[kk], cz);
      cin = mfma16(a1, wi2n[kk], cin);
      cr  = mfma16(a2, wh2r[kk], cr);
      cz  = mfma16(a2, wh2z[kk], cz);
      chn = mfma16(a2, wh2n[kk], chn);
    }
    float C2[4], rg2[4], zg2[4];
#pragma unroll
    for (int r = 0; r < 4; ++r) {
      float er = ex2(cr[r]);
      float ez = ex2(cz[r]);
      float A  = fmaf(er, eb2r, 1.f);
      float Bv = fmaf(ez, eb2z, 1.f);
      float R  = rcpa(A * Bv);
      rg2[r] = R * Bv; zg2[r] = R * A;
      float av = fmaf(rg2[r], chn[r] + b2hn, cin[r] + b2in);
      C2[r] = 1.f + ex2(av);
    }
#pragma unroll
    for (int p = 0; p < 4; p += 2) {
      float R2 = rcpa(C2[p] * C2[p + 1]);
      float m0 = fmaf(R2 * C2[p + 1], -2.f, 1.f);
      float m1 = fmaf(R2 * C2[p],     -2.f, 1.f);
      h2p[p]     = fmaf(zg2[p],     h2p[p]     - m0, m0);
      h2p[p + 1] = fmaf(zg2[p + 1], h2p[p + 1] - m1, m1);
    }
  }

  // ---------------- FC epilogue (pure fp32) ----------------
#pragma unroll
  for (int r = 0; r < 4; ++r) h2f[q * 4 + r][jc] = h2p[r];
  __syncthreads();
  if (tid < 384) {
    const int m = tid & 15;
    const int cls = tid >> 4;  // 0..23
    const float* w = fcw + cls * 128;
    float acc = fcb[cls];
#pragma unroll 8
    for (int j = 0; j < 128; ++j) acc = fmaf(h2f[m][j], w[j], acc);
    out[(size_t)(s0 + m) * 24 + cls] = acc;
  }
}

extern "C" void kernel_launch(void* const* d_in, const int* in_sizes, int n_in,
                              void* d_out, int out_size, void* d_ws, size_t ws_size,
                              hipStream_t stream) {
  (void)in_sizes; (void)n_in; (void)d_ws; (void)ws_size; (void)out_size;
  const float* x    = (const float*)d_in[0];
  const float* wih1 = (const float*)d_in[1];
  const float* whh1 = (const float*)d_in[2];
  const float* bih1 = (const float*)d_in[3];
  const float* bhh1 = (const float*)d_in[4];
  const float* wih2 = (const float*)d_in[5];
  const float* whh2 = (const float*)d_in[6];
  const float* bih2 = (const float*)d_in[7];
  const float* bhh2 = (const float*)d_in[8];
  const float* fcw  = (const float*)d_in[9];
  const float* fcb  = (const float*)d_in[10];
  float* outp = (float*)d_out;
  gru_fused<<<dim3(256), dim3(512), 0, stream>>>(
      x, wih1, whh1, bih1, bhh1, wih2, whh2, bih2, bhh2, fcw, fcb, outp);
}

// Round 7
// 259.894 us; speedup vs baseline: 1.0268x; 1.0268x over previous
//
#include <hip/hip_runtime.h>

// Fused 2-layer GRU + FC for (B=4096, L=128, IN=16, H=128, NC=24).
// 256 blocks x 512 threads (1 block/CU); block = 16 batch rows, wave w owns
// h-cols [16w,16w+16). Weights pinned in VGPRs/AGPRs via empty inline asm.
// Layer2 runs one step behind layer1 => single barrier per step, 39 MFMAs of
// ILP per barrier interval.
//
// Round 3:  epilogue trans diet (exp2 weights, shared rcp, zero-C MFMA) -> 210us.
// Round 4:  packed-f32 epilogue + reg prefetch -> REGRESSED (scratch spills).
// Round 5:  pk epilogue, clean staging -> 213.5us (latency- not issue-bound).
// Round 6:  x-projection hoist -> null (212us) + minor spill.
// Round 7:  ax guard dropped -> NaN (MFMA NaN*0=NaN from uninit LDS pad).
// Round 8:  conflict-free LDS strides (9.1M -> 147K conflicts) -> 216us:
//   conflicts were HIDDEN under barrier drain; 2x ds_read_b64 cost real issue
//   slots. 2-way conflicts are ~free (m136) -> revert to HS=136 + b128 reads.
// Round 9 (this version): exact round-3 (210us) structure + s_setprio(1)
//   around the MFMA cluster: between barriers the 2 waves/SIMD drift phase
//   (one in trans-epilogue, one issuing MFMA); prioritizing MFMA returns
//   each wave's accumulators sooner. Pure scheduling hint, numerics identical.

typedef _Float16 half_t;
typedef _Float16 half8 __attribute__((ext_vector_type(8)));
typedef _Float16 half4v __attribute__((ext_vector_type(4)));
typedef float f32x4 __attribute__((ext_vector_type(4)));

#define BB 16      // batch rows per block
#define HS 136     // h row stride (halves), 16B-aligned rows (2-way conflict: free)
#define XS 520     // x chunk row stride (halves): 32*16 + 8 pad

#define NL2E (-1.442695041f)   // -log2(e)  : r,z gates (sigmoid via 2^-x)
#define L2E2 (2.885390082f)    // 2*log2(e) : n gate    (tanh via 2^{2a*log2e})

static __device__ __forceinline__ f32x4 mfma16(half8 a, half8 b, f32x4 c) {
  return __builtin_amdgcn_mfma_f32_16x16x32_f16(a, b, c, 0, 0, 0);
}

// Pin a fragment into registers: value becomes asm-defined => cannot be
// rematerialized from global memory inside the recurrence loop.
static __device__ __forceinline__ void pin(half8& v) {
  f32x4 t = __builtin_bit_cast(f32x4, v);
  asm volatile("" : "+v"(t));
  v = __builtin_bit_cast(half8, t);
}

static __device__ __forceinline__ half8 zero8() {
  half8 v;
#pragma unroll
  for (int i = 0; i < 8; ++i) v[i] = (half_t)0.f;
  return v;
}

static __device__ __forceinline__ half8 ldw8s(const float* __restrict__ p, float s) {
  float4 a = *(const float4*)p;
  float4 b = *(const float4*)(p + 4);
  half8 r;
  r[0] = (half_t)(a.x * s); r[1] = (half_t)(a.y * s);
  r[2] = (half_t)(a.z * s); r[3] = (half_t)(a.w * s);
  r[4] = (half_t)(b.x * s); r[5] = (half_t)(b.y * s);
  r[6] = (half_t)(b.z * s); r[7] = (half_t)(b.w * s);
  return r;
}

static __device__ __forceinline__ float ex2(float x) { return __builtin_amdgcn_exp2f(x); }
static __device__ __forceinline__ float rcpa(float x) { return __builtin_amdgcn_rcpf(x); }

__global__ __launch_bounds__(512, 2) void gru_fused(
    const float* __restrict__ x,                                    // (4096,2,1024)
    const float* __restrict__ wih1, const float* __restrict__ whh1, // (384,16),(384,128)
    const float* __restrict__ bih1, const float* __restrict__ bhh1,
    const float* __restrict__ wih2, const float* __restrict__ whh2, // (384,128)x2
    const float* __restrict__ bih2, const float* __restrict__ bhh2,
    const float* __restrict__ fcw, const float* __restrict__ fcb,   // (24,128),(24,)
    float* __restrict__ out)                                        // (4096,24)
{
  __shared__ __align__(16) half_t xl[BB][XS];        // 16640 B
  __shared__ __align__(16) half_t h1b[2][BB][HS];    //  8704 B
  __shared__ __align__(16) half_t h2b[2][BB][HS];    //  8704 B
  __shared__ float h2f[BB][129];                     //  8256 B

  const int tid = threadIdx.x;
  const int lane = tid & 63;
  const int wv = tid >> 6;      // wave 0..7
  const int q = lane >> 4;      // quad 0..3
  const int c = lane & 15;
  const int jc = wv * 16 + c;   // this lane's h-column (0..127)
  const int s0 = blockIdx.x * BB;

  // zero both parity buffers of both states (layer2 MFMAs run unguarded at i=0)
  for (int i = tid; i < 2 * BB * HS; i += 512) {
    ((half_t*)h1b)[i] = (half_t)0.f;
    ((half_t*)h2b)[i] = (half_t)0.f;
  }

  // biases in log2-units. r/z biases fold multiplicatively: e^{-x-b} = 2^{acc}*eb.
  const float eb1r = ex2(NL2E * (bih1[jc] + bhh1[jc]));
  const float eb1z = ex2(NL2E * (bih1[128 + jc] + bhh1[128 + jc]));
  const float b1in = L2E2 * bih1[256 + jc];
  const float b1hn = L2E2 * bhh1[256 + jc];
  const float eb2r = ex2(NL2E * (bih2[jc] + bhh2[jc]));
  const float eb2z = ex2(NL2E * (bih2[128 + jc] + bhh2[128 + jc]));
  const float b2in = L2E2 * bih2[256 + jc];
  const float b2hn = L2E2 * bhh2[256 + jc];

  // weight B-fragments: lane holds W[n=jc(+g*128)][k = kk*32 + q*8 + j],
  // pre-scaled: r,z by -log2e; n by 2*log2e.
  half8 wi1r, wi1z, wi1n;
  if (q < 2) {  // real K=16, quads 2..3 are zero-pad
    wi1r = ldw8s(wih1 + (0 * 128 + jc) * 16 + q * 8, NL2E);
    wi1z = ldw8s(wih1 + (1 * 128 + jc) * 16 + q * 8, NL2E);
    wi1n = ldw8s(wih1 + (2 * 128 + jc) * 16 + q * 8, L2E2);
  } else {
    wi1r = zero8(); wi1z = zero8(); wi1n = zero8();
  }
  pin(wi1r); pin(wi1z); pin(wi1n);

  half8 wh1r[4], wh1z[4], wh1n[4], wi2r[4], wi2z[4], wi2n[4], wh2r[4], wh2z[4], wh2n[4];
#pragma unroll
  for (int kk = 0; kk < 4; ++kk) {
    const int ko = kk * 32 + q * 8;
    wh1r[kk] = ldw8s(whh1 + (0 * 128 + jc) * 128 + ko, NL2E);
    wh1z[kk] = ldw8s(whh1 + (1 * 128 + jc) * 128 + ko, NL2E);
    wh1n[kk] = ldw8s(whh1 + (2 * 128 + jc) * 128 + ko, L2E2);
    wi2r[kk] = ldw8s(wih2 + (0 * 128 + jc) * 128 + ko, NL2E);
    wi2z[kk] = ldw8s(wih2 + (1 * 128 + jc) * 128 + ko, NL2E);
    wi2n[kk] = ldw8s(wih2 + (2 * 128 + jc) * 128 + ko, L2E2);
    wh2r[kk] = ldw8s(whh2 + (0 * 128 + jc) * 128 + ko, NL2E);
    wh2z[kk] = ldw8s(whh2 + (1 * 128 + jc) * 128 + ko, NL2E);
    wh2n[kk] = ldw8s(whh2 + (2 * 128 + jc) * 128 + ko, L2E2);
    pin(wh1r[kk]); pin(wh1z[kk]); pin(wh1n[kk]);
    pin(wi2r[kk]); pin(wi2z[kk]); pin(wi2n[kk]);
    pin(wh2r[kk]); pin(wh2z[kk]); pin(wh2n[kk]);
  }

  // fp32 hidden state, lane-resident: rows m = 4q+r, col jc
  float h1p[4] = {0.f, 0.f, 0.f, 0.f};
  float h2p[4] = {0.f, 0.f, 0.f, 0.f};

#pragma unroll 1
  for (int tc = 0; tc < 4; ++tc) {
    // stage x[s][ch][tc*256 .. +255] -> xl[s][tl*16 + ch*8 + k], fp16
#pragma unroll
    for (int it = 0; it < 4; ++it) {
      int idx = tid + it * 512;         // 0..2047 float4s
      int s = idx >> 7;
      int rem = idx & 127;
      int ch = rem >> 6;
      int i4 = rem & 63;
      const float4 v = *(const float4*)(x + (size_t)(s0 + s) * 2048 + ch * 1024 + tc * 256 + i4 * 4);
      half4v hv;
      hv[0] = (half_t)v.x; hv[1] = (half_t)v.y; hv[2] = (half_t)v.z; hv[3] = (half_t)v.w;
      *(half4v*)&xl[s][(i4 >> 1) * 16 + ch * 8 + (i4 & 1) * 4] = hv;
    }
    __syncthreads();

#pragma unroll 2
    for (int tt = 0; tt < 32; ++tt) {
      const int i = tc * 32 + tt;      // layer1 step index; layer2 does step i-1
      const int rb = i & 1;            // compile-time after unroll-2
      const int wb = rb ^ 1;
      const float l2m = (i > 0) ? 1.f : 0.f;   // uniform; kills i=0 garbage h2
      const f32x4 kZ = {0.f, 0.f, 0.f, 0.f};

      half8 ax = zero8();
      if (q < 2) ax = *(const half8*)&xl[c][tt * 16 + q * 8];
      half8 ah0 = *(const half8*)&h1b[rb][c][q * 8];   // h1[i-1], kk=0
      half8 a20 = *(const half8*)&h2b[rb][c][q * 8];   // h2[i-2], kk=0

      // MFMA cluster: raise wave priority so a wave issuing MFMAs preempts
      // the other wave's epilogue VALU; its accumulators return sooner.
      __builtin_amdgcn_s_setprio(1);
      // all 12 chains start from a zero C operand (no bias-splat movs)
      f32x4 ar  = mfma16(ax, wi1r, kZ);
      f32x4 az  = mfma16(ax, wi1z, kZ);
      f32x4 ain = mfma16(ax, wi1n, kZ);
      f32x4 ahn = mfma16(ah0, wh1n[0], kZ);
      ar = mfma16(ah0, wh1r[0], ar);
      az = mfma16(ah0, wh1z[0], az);
      f32x4 cr  = mfma16(ah0, wi2r[0], kZ);
      f32x4 cz  = mfma16(ah0, wi2z[0], kZ);
      f32x4 cin = mfma16(ah0, wi2n[0], kZ);
      f32x4 chn = mfma16(a20, wh2n[0], kZ);
      cr = mfma16(a20, wh2r[0], cr);
      cz = mfma16(a20, wh2z[0], cz);
#pragma unroll
      for (int kk = 1; kk < 4; ++kk) {
        half8 ah = *(const half8*)&h1b[rb][c][kk * 32 + q * 8];  // h1[i-1]
        half8 a2 = *(const half8*)&h2b[rb][c][kk * 32 + q * 8];  // h2[i-2]
        ar  = mfma16(ah, wh1r[kk], ar);
        az  = mfma16(ah, wh1z[kk], az);
        ahn = mfma16(ah, wh1n[kk], ahn);
        cr  = mfma16(ah, wi2r[kk], cr);   // layer2 input = h1[i-1]
        cz  = mfma16(ah, wi2z[kk], cz);
        cin = mfma16(ah, wi2n[kk], cin);
        cr  = mfma16(a2, wh2r[kk], cr);
        cz  = mfma16(a2, wh2z[kk], cz);
        chn = mfma16(a2, wh2n[kk], chn);
      }
      __builtin_amdgcn_s_setprio(0);

      // ---- epilogue, both layers, scalar (max ILP) ----
      float C1[4], rg1[4], zg1[4], C2[4], rg2[4], zg2[4];
#pragma unroll
      for (int r = 0; r < 4; ++r) {
        float er = ex2(ar[r]);
        float ez = ex2(az[r]);
        float A  = fmaf(er, eb1r, 1.f);
        float Bv = fmaf(ez, eb1z, 1.f);
        float R  = rcpa(A * Bv);
        rg1[r] = R * Bv; zg1[r] = R * A;
        float av = fmaf(rg1[r], ahn[r] + b1hn, ain[r] + b1in);
        C1[r] = 1.f + ex2(av);
      }
#pragma unroll
      for (int r = 0; r < 4; ++r) {
        float er = ex2(cr[r]);
        float ez = ex2(cz[r]);
        float A  = fmaf(er, eb2r, 1.f);
        float Bv = fmaf(ez, eb2z, 1.f);
        float R  = rcpa(A * Bv);
        rg2[r] = R * Bv; zg2[r] = R * A;
        float av = fmaf(rg2[r], chn[r] + b2hn, cin[r] + b2in);
        C2[r] = 1.f + ex2(av);
      }
#pragma unroll
      for (int p = 0; p < 4; p += 2) {
        // layer1 tanh pair + update
        float R1 = rcpa(C1[p] * C1[p + 1]);
        float n0 = fmaf(R1 * C1[p + 1], -2.f, 1.f);
        float n1 = fmaf(R1 * C1[p],     -2.f, 1.f);
        float e0 = fmaf(zg1[p],     h1p[p]     - n0, n0);   // (1-z)n + z h
        float e1 = fmaf(zg1[p + 1], h1p[p + 1] - n1, n1);
        h1p[p] = e0; h1p[p + 1] = e1;
        h1b[wb][q * 4 + p][jc]     = (half_t)e0;
        h1b[wb][q * 4 + p + 1][jc] = (half_t)e1;
        // layer2 tanh pair + masked update (mask=0 only at i==0)
        float R2 = rcpa(C2[p] * C2[p + 1]);
        float m0 = fmaf(R2 * C2[p + 1], -2.f, 1.f);
        float m1 = fmaf(R2 * C2[p],     -2.f, 1.f);
        float g0 = fmaf(zg2[p],     h2p[p]     - m0, m0) * l2m;
        float g1 = fmaf(zg2[p + 1], h2p[p + 1] - m1, m1) * l2m;
        h2p[p] = g0; h2p[p + 1] = g1;
        h2b[wb][q * 4 + p][jc]     = (half_t)g0;
        h2b[wb][q * 4 + p + 1][jc] = (half_t)g1;
      }
      __syncthreads();
    }
  }

  // final layer2 step 127: h1[127] & h2[126] live in parity-0 buffers (i=128)
  {
    const f32x4 kZ = {0.f, 0.f, 0.f, 0.f};
    half8 a10 = *(const half8*)&h1b[0][c][q * 8];
    half8 a20 = *(const half8*)&h2b[0][c][q * 8];
    f32x4 cr  = mfma16(a10, wi2r[0], kZ);
    f32x4 cz  = mfma16(a10, wi2z[0], kZ);
    f32x4 cin = mfma16(a10, wi2n[0], kZ);
    f32x4 chn = mfma16(a20, wh2n[0], kZ);
    cr = mfma16(a20, wh2r[0], cr);
    cz = mfma16(a20, wh2z[0], cz);
#pragma unroll
    for (int kk = 1; kk < 4; ++kk) {
      half8 a1 = *(const half8*)&h1b[0][c][kk * 32 + q * 8];
      half8 a2 = *(const half8*)&h2b[0][c][kk * 32 + q * 8];
      cr  = mfma16(a1, wi2r[kk], cr);
      cz  = mfma16(a1, wi2z[kk], cz);
      cin = mfma16(a1, wi2n[kk], cin);
      cr  = mfma16(a2, wh2r[kk], cr);
      cz  = mfma16(a2, wh2z[kk], cz);
      chn = mfma16(a2, wh2n[kk], chn);
    }
    float C2[4], rg2[4], zg2[4];
#pragma unroll
    for (int r = 0; r < 4; ++r) {
      float er = ex2(cr[r]);
      float ez = ex2(cz[r]);
      float A  = fmaf(er, eb2r, 1.f);
      float Bv = fmaf(ez, eb2z, 1.f);
      float R  = rcpa(A * Bv);
      rg2[r] = R * Bv; zg2[r] = R * A;
      float av = fmaf(rg2[r], chn[r] + b2hn, cin[r] + b2in);
      C2[r] = 1.f + ex2(av);
    }
#pragma unroll
    for (int p = 0; p < 4; p += 2) {
      float R2 = rcpa(C2[p] * C2[p + 1]);
      float m0 = fmaf(R2 * C2[p + 1], -2.f, 1.f);
      float m1 = fmaf(R2 * C2[p],     -2.f, 1.f);
      h2p[p]     = fmaf(zg2[p],     h2p[p]     - m0, m0);
      h2p[p + 1] = fmaf(zg2[p + 1], h2p[p + 1] - m1, m1);
    }
  }

  // ---------------- FC epilogue (pure fp32) ----------------
#pragma unroll
  for (int r = 0; r < 4; ++r) h2f[q * 4 + r][jc] = h2p[r];
  __syncthreads();
  if (tid < 384) {
    const int m = tid & 15;
    const int cls = tid >> 4;  // 0..23
    const float* w = fcw + cls * 128;
    float acc = fcb[cls];
#pragma unroll 8
    for (int j = 0; j < 128; ++j) acc = fmaf(h2f[m][j], w[j], acc);
    out[(size_t)(s0 + m) * 24 + cls] = acc;
  }
}

extern "C" void kernel_launch(void* const* d_in, const int* in_sizes, int n_in,
                              void* d_out, int out_size, void* d_ws, size_t ws_size,
                              hipStream_t stream) {
  (void)in_sizes; (void)n_in; (void)d_ws; (void)ws_size; (void)out_size;
  const float* x    = (const float*)d_in[0];
  const float* wih1 = (const float*)d_in[1];
  const float* whh1 = (const float*)d_in[2];
  const float* bih1 = (const float*)d_in[3];
  const float* bhh1 = (const float*)d_in[4];
  const float* wih2 = (const float*)d_in[5];
  const float* whh2 = (const float*)d_in[6];
  const float* bih2 = (const float*)d_in[7];
  const float* bhh2 = (const float*)d_in[8];
  const float* fcw  = (const float*)d_in[9];
  const float* fcb  = (const float*)d_in[10];
  float* outp = (float*)d_out;
  gru_fused<<<dim3(256), dim3(512), 0, stream>>>(
      x, wih1, whh1, bih1, bhh1, wih2, whh2, bih2, bhh2, fcw, fcb, outp);
}